// Round 13
// baseline (936.160 us; speedup 1.0000x reference)
//
#include <hip/hip_runtime.h>

#define NPER 4096
#define MPER 1024
#define KNB 64
#define NB 4
#define CAP 1024
#define NWORK 128   // total blocks: 4 producers + 124 workers (throttle test)

typedef __attribute__((ext_vector_type(8))) short short8_t;
typedef __attribute__((ext_vector_type(4))) float f32x4;
typedef __attribute__((ext_vector_type(2))) float f32x2;

__device__ __forceinline__ unsigned short f2bf(float f) {
  union { float f; unsigned u; } v; v.f = f;
  unsigned r = v.u + 0x7fffu + ((v.u >> 16) & 1u);
  return (unsigned short)(r >> 16);
}

// packed fp32 (VOP3P): IEEE rn, bit-exact, compact
__device__ __forceinline__ f32x2 pk_add(f32x2 a, f32x2 b) {
  f32x2 d; asm("v_pk_add_f32 %0, %1, %2" : "=v"(d) : "v"(a), "v"(b)); return d;
}
__device__ __forceinline__ f32x2 pk_mul(f32x2 a, f32x2 b) {
  f32x2 d; asm("v_pk_mul_f32 %0, %1, %2" : "=v"(d) : "v"(a), "v"(b)); return d;
}

// LDS-only barrier (measured ≈ __syncthreads; keeps publish stores un-drained)
__device__ __forceinline__ void lds_barrier() {
  asm volatile("s_waitcnt lgkmcnt(0)" ::: "memory");
  __builtin_amdgcn_s_barrier();
  asm volatile("" ::: "memory");
}

#define DPP_KEY_STEP(ctrl)                                                            \
  {                                                                                   \
    unsigned lo = (unsigned)k, hi = (unsigned)(k >> 32);                              \
    unsigned tlo = (unsigned)__builtin_amdgcn_update_dpp((int)lo, (int)lo, ctrl, 0xF, 0xF, false); \
    unsigned thi = (unsigned)__builtin_amdgcn_update_dpp((int)hi, (int)hi, ctrl, 0xF, 0xF, false); \
    unsigned long long tk = ((unsigned long long)thi << 32) | tlo;                    \
    if (tk > k) k = tk;                                                               \
  }

#define U64MAX(a, b) (((a) > (b)) ? (a) : (b))

// ------- prep: weight swizzles + idx sentinel fill + queue counter zero -------
__global__ __launch_bounds__(256) void prep_kernel(const float* __restrict__ W1,
                                                   const float* __restrict__ W2,
                                                   unsigned short* __restrict__ w1f,
                                                   unsigned short* __restrict__ w2f,
                                                   int* __restrict__ idxg,
                                                   int* __restrict__ control) {
  const int f = blockIdx.x * 256 + threadIdx.x;
  if (f < 12288) {  // W1 frags: 8 nt * 3 kt * 64 lanes * 8 e
    const int frag = f >> 9, r = f & 511, lane = r >> 3, e = r & 7;
    const int nt = frag / 3, kt = frag % 3;
    const int n = nt * 16 + (lane & 15);
    const int k = kt * 32 + (lane >> 4) * 8 + e;
    float v = (k < 67) ? W1[k * 128 + n] : 0.f;
    w1f[f] = f2bf(v);
  } else if (f < 45056) {  // W2 frags: 16 nt * 4 kt * 64 * 8
    const int g = f - 12288;
    const int frag = g >> 9, r = g & 511, lane = r >> 3, e = r & 7;
    const int nt = frag >> 2, kt = frag & 3;
    const int n = nt * 16 + (lane & 15);
    const int k = kt * 32 + (lane >> 4) * 8 + e;
    w2f[g] = f2bf(W2[k * 256 + n]);
  } else if (f < 45056 + NB * MPER) {  // idxg sentinel: value IS the ready-flag
    idxg[f - 45056] = -1;
  } else if (f < 45056 + NB * MPER + 8) {
    control[f - 45056 - NB * MPER] = 0;
  }
}

// ============ fused: blocks 0-3 = FPS producers, rest = ballq+MLP consumers ============
__global__ __launch_bounds__(256) void fused_kernel(const float* __restrict__ x,
                                                    const float* __restrict__ pos,
                                                    const float* __restrict__ weight,
                                                    const unsigned short* __restrict__ w1f,
                                                    const unsigned short* __restrict__ w2f,
                                                    const float* __restrict__ b1,
                                                    const float* __restrict__ b2,
                                                    int* __restrict__ idxg,
                                                    int* __restrict__ control,
                                                    float* __restrict__ out) {
  // ---- FPS LDS ----
  __shared__ float4 p4[NPER];                              // 64 KiB
  __shared__ alignas(16) unsigned long long candk[2][4];
  __shared__ int s_idx[MPER];                              // staged indices
  // ---- worker LDS ----
  __shared__ float cd[CAP];
  __shared__ int   ci[CAP];
  __shared__ int   s_cnt;
  __shared__ alignas(16) unsigned short s_msg[64][104];
  __shared__ alignas(16) unsigned short s_h1[64][136];
  __shared__ int   s_valid[64];
  __shared__ float s_red[4][256];
  __shared__ int   s_w, s_qi;

  int* ctr = control;              // work-queue counter

  const int t = threadIdx.x;
  const int wave = t >> 6, lane = t & 63;

  if (blockIdx.x < NB) {
    // ========== FPS producer: exact r10 structure (best measured fused) ==========
    const int b = blockIdx.x;
    const int base = b * NPER;
    const int wid = wave;

    for (int i = t; i < NPER; i += 256) {
      p4[i] = make_float4(pos[(size_t)(base + i) * 3 + 0],
                          pos[(size_t)(base + i) * 3 + 1],
                          pos[(size_t)(base + i) * 3 + 2], 0.f);
    }
    __syncthreads();

    f32x2 pxp[8], pyp[8], pzp[8];
    float mnd[16];
    const int i0 = t * 16;
#pragma unroll
    for (int p = 0; p < 8; ++p) {
      float4 a = p4[i0 + 2 * p];
      float4 c = p4[i0 + 2 * p + 1];
      pxp[p] = (f32x2){a.x, c.x};
      pyp[p] = (f32x2){a.y, c.y};
      pzp[p] = (f32x2){a.z, c.z};
    }
#pragma unroll
    for (int j = 0; j < 16; ++j) mnd[j] = __builtin_inff();

    int last = 0;
    for (int it = 0; it < MPER; ++it) {
      if (t == 0) s_idx[it] = last;                 // LDS stage
      // burst-publish previous 32 indices once per 32 iters (wave 0, lanes 0-31)
      if (wid == 0 && lane < 32 && (it & 31) == 0 && it != 0) {
        int v = s_idx[it - 32 + lane];
        __hip_atomic_store(&idxg[b * MPER + it - 32 + lane], v,
                           __ATOMIC_RELAXED, __HIP_MEMORY_SCOPE_AGENT);
      }
      if (it == MPER - 1) break;
      const float4 q = p4[last];
      const f32x2 nqx = (f32x2){-q.x, -q.x};
      const f32x2 nqy = (f32x2){-q.y, -q.y};
      const f32x2 nqz = (f32x2){-q.z, -q.z};
      float bv = -1.0f; int bj = 0;
#pragma unroll
      for (int p = 0; p < 8; ++p) {
        f32x2 dx = pk_add(pxp[p], nqx);
        f32x2 dy = pk_add(pyp[p], nqy);
        f32x2 dz = pk_add(pzp[p], nqz);
        // (dx*dx + dy*dy) + dz*dz left-to-right, no fma (asm opaque to fusion)
        f32x2 s = pk_add(pk_add(pk_mul(dx, dx), pk_mul(dy, dy)), pk_mul(dz, dz));
        float m0 = fminf(mnd[2 * p], s.x);     mnd[2 * p] = m0;
        if (m0 > bv) { bv = m0; bj = 2 * p; }      // argmax fused in-loop (r10-proven)
        float m1 = fminf(mnd[2 * p + 1], s.y); mnd[2 * p + 1] = m1;
        if (m1 > bv) { bv = m1; bj = 2 * p + 1; }
      }
      const int bi = i0 + bj;
      union { float f; unsigned u; } fu; fu.f = bv;
      unsigned long long k = ((unsigned long long)fu.u << 32) | (0xFFFFFFFFu - (unsigned)bi);
      DPP_KEY_STEP(0x128)
      DPP_KEY_STEP(0x124)
      DPP_KEY_STEP(0x122)
      DPP_KEY_STEP(0x121)
      DPP_KEY_STEP(0x142)
      DPP_KEY_STEP(0x143)
      if (lane == 63) candk[it & 1][wid] = k;
      lds_barrier();
      const ulonglong2* ck = (const ulonglong2*)&candk[it & 1][0];
      ulonglong2 c0 = ck[0], c1 = ck[1];
      unsigned long long m0 = U64MAX(c0.x, c0.y);
      unsigned long long m1 = U64MAX(c1.x, c1.y);
      unsigned long long mg = U64MAX(m0, m1);
      last = (int)(0xFFFFFFFFu - (unsigned)mg);
    }
    lds_barrier();                                  // make s_idx[992..1023] visible
    if (wid == 0 && lane < 32) {
      int v = s_idx[992 + lane];
      __hip_atomic_store(&idxg[b * MPER + 992 + lane], v,
                         __ATOMIC_RELAXED, __HIP_MEMORY_SCOPE_AGENT);
    }
    return;
  }

  // ================= worker: dynamic queue of 4096 centroids =================
  for (;;) {
    if (t == 0) {
      s_cnt = 0;
      s_w = atomicAdd(ctr, 1);
    }
    __syncthreads();
    const int w = s_w;
    if (w >= NB * MPER) return;
    const int cloud = w & 3;
    const int m = w >> 2;
    const int c = cloud * MPER + m;
    const int base = cloud * NPER;

    if (t == 0) {
      int v;
      while ((v = __hip_atomic_load(&idxg[c], __ATOMIC_RELAXED,
                                    __HIP_MEMORY_SCOPE_AGENT)) < 0)
        __builtin_amdgcn_s_sleep(8);
      s_qi = v;                  // single word: data IS the flag
    }
    __syncthreads();
    const int qi = s_qi;

    const float q0 = pos[(size_t)(base + qi) * 3 + 0];
    const float q1 = pos[(size_t)(base + qi) * 3 + 1];
    const float q2 = pos[(size_t)(base + qi) * 3 + 2];
    const float r2f = (float)(0.2 * 0.2);

    // ---- radius filter (reference-exact d2)
#pragma unroll
    for (int s = 0; s < 16; ++s) {
      const int i = t + s * 256;
      float dx = __fsub_rn(q0, pos[(size_t)(base + i) * 3 + 0]);
      float dy = __fsub_rn(q1, pos[(size_t)(base + i) * 3 + 1]);
      float dz = __fsub_rn(q2, pos[(size_t)(base + i) * 3 + 2]);
      float d = __fadd_rn(__fadd_rn(__fmul_rn(dx, dx), __fmul_rn(dy, dy)), __fmul_rn(dz, dz));
      if (d <= r2f) {
        int p = atomicAdd(&s_cnt, 1);
        if (p < CAP) { cd[p] = d; ci[p] = i; }
      }
    }
    __syncthreads();
    int n = s_cnt; if (n > CAP) n = CAP;
    if (n > KNB) {
      int P = 64; while (P < n) P <<= 1;
      for (int i = n + t; i < P; i += 256) { cd[i] = __builtin_inff(); ci[i] = 0x7fffffff; }
      __syncthreads();
      for (int k2 = 2; k2 <= P; k2 <<= 1) {
        for (int j = k2 >> 1; j > 0; j >>= 1) {
          for (int i = t; i < P; i += 256) {
            const int ixj = i ^ j;
            if (ixj > i) {
              const bool up = ((i & k2) == 0);
              float a = cd[i], bb = cd[ixj];
              int ia = ci[i], ib = ci[ixj];
              const bool gt = (a > bb) || (a == bb && ia > ib);
              if (gt == up) { cd[i] = bb; cd[ixj] = a; ci[i] = ib; ci[ixj] = ia; }
            }
          }
          __syncthreads();
        }
      }
    }

    const int nn = (n < KNB) ? n : KNB;
    const int nbrv = (lane < nn) ? ci[lane] : -1;
    s_valid[lane] = (lane < nn) ? 1 : 0;

    // ---- gather msg = [x_j | rel | 0-pad] as bf16
#pragma unroll 4
    for (int i = 0; i < 16; ++i) {
      const int k = wave * 16 + i;
      const int j = __shfl(nbrv, k, 64);
      float f = 0.f;
      if (j >= 0) f = x[(size_t)(base + j) * 64 + lane];
      s_msg[k][lane] = f2bf(f);
      if (lane < 40) {
        float rv = 0.f;
        if (lane < 3 && j >= 0) {
          float p = pos[(size_t)(base + j) * 3 + lane];
          float qq = (lane == 0) ? q0 : ((lane == 1) ? q1 : q2);
          rv = __fsub_rn(p, qq);
        }
        s_msg[k][64 + lane] = f2bf(rv);
      }
    }
    __syncthreads();

    const int row = wave * 16 + (lane & 15);
    const int kofs = (lane >> 4) * 8;

    // ---- GEMM1
    short8_t a1[3];
#pragma unroll
    for (int kt = 0; kt < 3; ++kt)
      a1[kt] = *(const short8_t*)&s_msg[row][kt * 32 + kofs];
    f32x4 acc1[8];
#pragma unroll
    for (int nt = 0; nt < 8; ++nt) acc1[nt] = (f32x4){0.f, 0.f, 0.f, 0.f};
#pragma unroll
    for (int kt = 0; kt < 3; ++kt) {
#pragma unroll
      for (int nt = 0; nt < 8; ++nt) {
        short8_t bf = *(const short8_t*)&w1f[((nt * 3 + kt) * 64 + lane) * 8];
        acc1[nt] = __builtin_amdgcn_mfma_f32_16x16x32_bf16(a1[kt], bf, acc1[nt], 0, 0, 0);
      }
    }
#pragma unroll
    for (int nt = 0; nt < 8; ++nt) {
      const int n2 = nt * 16 + (lane & 15);
      const float bias = b1[n2];
      f32x4 v = acc1[nt];
#pragma unroll
      for (int e = 0; e < 4; ++e) {
        const int mm2 = wave * 16 + (lane >> 4) * 4 + e;
        float h = v[e] + bias;
        h = (h > 0.f) ? h : 0.f;
        s_h1[mm2][n2] = f2bf(h);
      }
    }
    __syncthreads();

    // ---- GEMM2 + mask + max over k
    short8_t a2[4];
#pragma unroll
    for (int kt = 0; kt < 4; ++kt)
      a2[kt] = *(const short8_t*)&s_h1[row][kt * 32 + kofs];
    f32x4 acc2[16];
#pragma unroll
    for (int nt = 0; nt < 16; ++nt) acc2[nt] = (f32x4){0.f, 0.f, 0.f, 0.f};
#pragma unroll
    for (int kt = 0; kt < 4; ++kt) {
#pragma unroll
      for (int nt = 0; nt < 16; ++nt) {
        short8_t bf = *(const short8_t*)&w2f[((nt * 4 + kt) * 64 + lane) * 8];
        acc2[nt] = __builtin_amdgcn_mfma_f32_16x16x32_bf16(a2[kt], bf, acc2[nt], 0, 0, 0);
      }
    }
    const int m0i = wave * 16 + (lane >> 4) * 4;
    const int vld0 = s_valid[m0i + 0], vld1 = s_valid[m0i + 1];
    const int vld2 = s_valid[m0i + 2], vld3 = s_valid[m0i + 3];
#pragma unroll
    for (int nt = 0; nt < 16; ++nt) {
      const int n2 = nt * 16 + (lane & 15);
      const float bias = b2[n2];
      f32x4 d = acc2[nt];
      float best = -__builtin_inff();
      {
        float h;
        h = d[0] + bias; h = (h > 0.f) ? h : 0.f; if (vld0) best = fmaxf(best, h);
        h = d[1] + bias; h = (h > 0.f) ? h : 0.f; if (vld1) best = fmaxf(best, h);
        h = d[2] + bias; h = (h > 0.f) ? h : 0.f; if (vld2) best = fmaxf(best, h);
        h = d[3] + bias; h = (h > 0.f) ? h : 0.f; if (vld3) best = fmaxf(best, h);
      }
      best = fmaxf(best, __shfl_xor(best, 16, 64));
      best = fmaxf(best, __shfl_xor(best, 32, 64));
      if ((lane >> 4) == 0) s_red[wave][n2] = best;
    }
    __syncthreads();
    const float r = fmaxf(fmaxf(s_red[0][t], s_red[1][t]), fmaxf(s_red[2][t], s_red[3][t]));
    out[(size_t)c * 256 + t] = r;

    // ---- tail for this centroid
    if (t < 5) {
      const int g = base + qi;
      float* pos_out = out + 1048576;
      float* batch_out = out + 1048576 + 12288;
      float* w_out = out + 1048576 + 12288 + 4096;
      if (t < 3)      pos_out[c * 3 + t] = pos[(size_t)g * 3 + t];
      else if (t == 3) batch_out[c] = (float)cloud;
      else             w_out[c] = weight[g];
    }
    __syncthreads();   // all threads done with LDS before next item resets
  }
}

extern "C" void kernel_launch(void* const* d_in, const int* in_sizes, int n_in,
                              void* d_out, int out_size, void* d_ws, size_t ws_size,
                              hipStream_t stream) {
  const float* x      = (const float*)d_in[0];
  const float* pos    = (const float*)d_in[1];
  // d_in[2] = batch (unused: batch = global_index / NPER by construction)
  const float* weight = (const float*)d_in[3];
  const float* W1     = (const float*)d_in[4];
  const float* b1     = (const float*)d_in[5];
  const float* W2     = (const float*)d_in[6];
  const float* b2     = (const float*)d_in[7];
  float* out = (float*)d_out;

  char* ws = (char*)d_ws;
  int* idxg = (int*)ws;                                    // 4096 * 4B (sentinel -1)
  unsigned short* w1f = (unsigned short*)(ws + 16384);     // 12288 * 2B
  unsigned short* w2f = (unsigned short*)(ws + 40960);     // 32768 * 2B
  int* control = (int*)(ws + 106496);                      // ctr @0

  prep_kernel<<<193, 256, 0, stream>>>(W1, W2, w1f, w2f, idxg, control);
  fused_kernel<<<NWORK, 256, 0, stream>>>(x, pos, weight, w1f, w2f, b1, b2,
                                          idxg, control, out);
}

// Round 14
// 669.628 us; speedup vs baseline: 1.3980x; 1.3980x over previous
//
#include <hip/hip_runtime.h>

#define NPER 4096
#define MPER 1024
#define KNB 64
#define NB 4
#define CAP 1024
#define NWORK 256   // 4 producers + 252 workers (r10 champion config)

typedef __attribute__((ext_vector_type(8))) short short8_t;
typedef __attribute__((ext_vector_type(4))) float f32x4;
typedef __attribute__((ext_vector_type(2))) float f32x2;

__device__ __forceinline__ unsigned short f2bf(float f) {
  union { float f; unsigned u; } v; v.f = f;
  unsigned r = v.u + 0x7fffu + ((v.u >> 16) & 1u);
  return (unsigned short)(r >> 16);
}

// packed fp32 (VOP3P): IEEE rn, bit-exact, compact
__device__ __forceinline__ f32x2 pk_add(f32x2 a, f32x2 b) {
  f32x2 d; asm("v_pk_add_f32 %0, %1, %2" : "=v"(d) : "v"(a), "v"(b)); return d;
}
__device__ __forceinline__ f32x2 pk_mul(f32x2 a, f32x2 b) {
  f32x2 d; asm("v_pk_mul_f32 %0, %1, %2" : "=v"(d) : "v"(a), "v"(b)); return d;
}

// LDS-only barrier (measured ≈ __syncthreads; keeps publish stores un-drained)
__device__ __forceinline__ void lds_barrier() {
  asm volatile("s_waitcnt lgkmcnt(0)" ::: "memory");
  __builtin_amdgcn_s_barrier();
  asm volatile("" ::: "memory");
}

#define DPP_KEY_STEP(ctrl)                                                            \
  {                                                                                   \
    unsigned lo = (unsigned)k, hi = (unsigned)(k >> 32);                              \
    unsigned tlo = (unsigned)__builtin_amdgcn_update_dpp((int)lo, (int)lo, ctrl, 0xF, 0xF, false); \
    unsigned thi = (unsigned)__builtin_amdgcn_update_dpp((int)hi, (int)hi, ctrl, 0xF, 0xF, false); \
    unsigned long long tk = ((unsigned long long)thi << 32) | tlo;                    \
    if (tk > k) k = tk;                                                               \
  }

#define U64MAX(a, b) (((a) > (b)) ? (a) : (b))

// ------- prep: weight swizzles + idx sentinel fill + queue counter zero -------
__global__ __launch_bounds__(256) void prep_kernel(const float* __restrict__ W1,
                                                   const float* __restrict__ W2,
                                                   unsigned short* __restrict__ w1f,
                                                   unsigned short* __restrict__ w2f,
                                                   int* __restrict__ idxg,
                                                   int* __restrict__ control) {
  const int f = blockIdx.x * 256 + threadIdx.x;
  if (f < 12288) {  // W1 frags: 8 nt * 3 kt * 64 lanes * 8 e
    const int frag = f >> 9, r = f & 511, lane = r >> 3, e = r & 7;
    const int nt = frag / 3, kt = frag % 3;
    const int n = nt * 16 + (lane & 15);
    const int k = kt * 32 + (lane >> 4) * 8 + e;
    float v = (k < 67) ? W1[k * 128 + n] : 0.f;
    w1f[f] = f2bf(v);
  } else if (f < 45056) {  // W2 frags: 16 nt * 4 kt * 64 * 8
    const int g = f - 12288;
    const int frag = g >> 9, r = g & 511, lane = r >> 3, e = r & 7;
    const int nt = frag >> 2, kt = frag & 3;
    const int n = nt * 16 + (lane & 15);
    const int k = kt * 32 + (lane >> 4) * 8 + e;
    w2f[g] = f2bf(W2[k * 256 + n]);
  } else if (f < 45056 + NB * MPER) {  // idxg sentinel: value IS the ready-flag
    idxg[f - 45056] = -1;
  } else if (f < 45056 + NB * MPER + 8) {
    control[f - 45056 - NB * MPER] = 0;
  }
}

// ============ fused: blocks 0-3 = FPS producers, rest = ballq+MLP consumers ============
__global__ __launch_bounds__(256) void fused_kernel(const float* __restrict__ x,
                                                    const float* __restrict__ pos,
                                                    const float* __restrict__ weight,
                                                    const unsigned short* __restrict__ w1f,
                                                    const unsigned short* __restrict__ w2f,
                                                    const float* __restrict__ b1,
                                                    const float* __restrict__ b2,
                                                    int* __restrict__ idxg,
                                                    int* __restrict__ control,
                                                    float* __restrict__ out) {
  // ---- FPS LDS ----
  __shared__ float4 p4[NPER];                              // 64 KiB
  __shared__ alignas(16) unsigned long long candk[2][4];
  __shared__ int s_idx[MPER];                              // staged indices
  // ---- worker LDS ----
  __shared__ float cd[CAP];
  __shared__ int   ci[CAP];
  __shared__ int   s_cnt;
  __shared__ alignas(16) unsigned short s_msg[64][104];
  __shared__ alignas(16) unsigned short s_h1[64][136];
  __shared__ int   s_valid[64];
  __shared__ float s_red[4][256];
  __shared__ int   s_w, s_qi;

  int* ctr = control;              // work-queue counter

  const int t = threadIdx.x;
  const int wave = t >> 6, lane = t & 63;

  if (blockIdx.x < NB) {
    // ========== FPS producer: exact r10 structure (champion, 672 us) ==========
    const int b = blockIdx.x;
    const int base = b * NPER;
    const int wid = wave;

    for (int i = t; i < NPER; i += 256) {
      p4[i] = make_float4(pos[(size_t)(base + i) * 3 + 0],
                          pos[(size_t)(base + i) * 3 + 1],
                          pos[(size_t)(base + i) * 3 + 2], 0.f);
    }
    __syncthreads();

    f32x2 pxp[8], pyp[8], pzp[8];
    float mnd[16];
    const int i0 = t * 16;
#pragma unroll
    for (int p = 0; p < 8; ++p) {
      float4 a = p4[i0 + 2 * p];
      float4 c = p4[i0 + 2 * p + 1];
      pxp[p] = (f32x2){a.x, c.x};
      pyp[p] = (f32x2){a.y, c.y};
      pzp[p] = (f32x2){a.z, c.z};
    }
#pragma unroll
    for (int j = 0; j < 16; ++j) mnd[j] = __builtin_inff();

    int last = 0;
    for (int it = 0; it < MPER; ++it) {
      if (t == 0) s_idx[it] = last;                 // LDS stage
      // burst-publish previous 32 indices once per 32 iters (wave 0, lanes 0-31)
      if (wid == 0 && lane < 32 && (it & 31) == 0 && it != 0) {
        int v = s_idx[it - 32 + lane];
        __hip_atomic_store(&idxg[b * MPER + it - 32 + lane], v,
                           __ATOMIC_RELAXED, __HIP_MEMORY_SCOPE_AGENT);
      }
      if (it == MPER - 1) break;
      const float4 q = p4[last];
      const f32x2 nqx = (f32x2){-q.x, -q.x};
      const f32x2 nqy = (f32x2){-q.y, -q.y};
      const f32x2 nqz = (f32x2){-q.z, -q.z};
      float bv = -1.0f; int bj = 0;
#pragma unroll
      for (int p = 0; p < 8; ++p) {
        f32x2 dx = pk_add(pxp[p], nqx);
        f32x2 dy = pk_add(pyp[p], nqy);
        f32x2 dz = pk_add(pzp[p], nqz);
        // (dx*dx + dy*dy) + dz*dz left-to-right, no fma (asm opaque to fusion)
        f32x2 s = pk_add(pk_add(pk_mul(dx, dx), pk_mul(dy, dy)), pk_mul(dz, dz));
        float m0 = fminf(mnd[2 * p], s.x);     mnd[2 * p] = m0;
        if (m0 > bv) { bv = m0; bj = 2 * p; }      // argmax fused in-loop
        float m1 = fminf(mnd[2 * p + 1], s.y); mnd[2 * p + 1] = m1;
        if (m1 > bv) { bv = m1; bj = 2 * p + 1; }
      }
      const int bi = i0 + bj;
      union { float f; unsigned u; } fu; fu.f = bv;
      unsigned long long k = ((unsigned long long)fu.u << 32) | (0xFFFFFFFFu - (unsigned)bi);
      DPP_KEY_STEP(0x128)
      DPP_KEY_STEP(0x124)
      DPP_KEY_STEP(0x122)
      DPP_KEY_STEP(0x121)
      DPP_KEY_STEP(0x142)
      DPP_KEY_STEP(0x143)
      if (lane == 63) candk[it & 1][wid] = k;
      lds_barrier();
      const ulonglong2* ck = (const ulonglong2*)&candk[it & 1][0];
      ulonglong2 c0 = ck[0], c1 = ck[1];
      unsigned long long m0 = U64MAX(c0.x, c0.y);
      unsigned long long m1 = U64MAX(c1.x, c1.y);
      unsigned long long mg = U64MAX(m0, m1);
      last = (int)(0xFFFFFFFFu - (unsigned)mg);
    }
    lds_barrier();                                  // make s_idx[992..1023] visible
    if (wid == 0 && lane < 32) {
      int v = s_idx[992 + lane];
      __hip_atomic_store(&idxg[b * MPER + 992 + lane], v,
                         __ATOMIC_RELAXED, __HIP_MEMORY_SCOPE_AGENT);
    }
    return;
  }

  // ================= worker: dynamic queue of 4096 centroids =================
  for (;;) {
    if (t == 0) {
      s_cnt = 0;
      s_w = atomicAdd(ctr, 1);
    }
    __syncthreads();
    const int w = s_w;
    if (w >= NB * MPER) return;
    const int cloud = w & 3;
    const int m = w >> 2;
    const int c = cloud * MPER + m;
    const int base = cloud * NPER;

    if (t == 0) {
      int v;
      while ((v = __hip_atomic_load(&idxg[c], __ATOMIC_RELAXED,
                                    __HIP_MEMORY_SCOPE_AGENT)) < 0)
        __builtin_amdgcn_s_sleep(8);
      s_qi = v;                  // single word: data IS the flag
    }
    __syncthreads();
    const int qi = s_qi;

    const float q0 = pos[(size_t)(base + qi) * 3 + 0];
    const float q1 = pos[(size_t)(base + qi) * 3 + 1];
    const float q2 = pos[(size_t)(base + qi) * 3 + 2];
    const float r2f = (float)(0.2 * 0.2);

    // ---- radius filter (reference-exact d2)
#pragma unroll
    for (int s = 0; s < 16; ++s) {
      const int i = t + s * 256;
      float dx = __fsub_rn(q0, pos[(size_t)(base + i) * 3 + 0]);
      float dy = __fsub_rn(q1, pos[(size_t)(base + i) * 3 + 1]);
      float dz = __fsub_rn(q2, pos[(size_t)(base + i) * 3 + 2]);
      float d = __fadd_rn(__fadd_rn(__fmul_rn(dx, dx), __fmul_rn(dy, dy)), __fmul_rn(dz, dz));
      if (d <= r2f) {
        int p = atomicAdd(&s_cnt, 1);
        if (p < CAP) { cd[p] = d; ci[p] = i; }
      }
    }
    __syncthreads();
    int n = s_cnt; if (n > CAP) n = CAP;
    if (n > KNB) {
      int P = 64; while (P < n) P <<= 1;
      for (int i = n + t; i < P; i += 256) { cd[i] = __builtin_inff(); ci[i] = 0x7fffffff; }
      __syncthreads();
      for (int k2 = 2; k2 <= P; k2 <<= 1) {
        for (int j = k2 >> 1; j > 0; j >>= 1) {
          for (int i = t; i < P; i += 256) {
            const int ixj = i ^ j;
            if (ixj > i) {
              const bool up = ((i & k2) == 0);
              float a = cd[i], bb = cd[ixj];
              int ia = ci[i], ib = ci[ixj];
              const bool gt = (a > bb) || (a == bb && ia > ib);
              if (gt == up) { cd[i] = bb; cd[ixj] = a; ci[i] = ib; ci[ixj] = ia; }
            }
          }
          __syncthreads();
        }
      }
    }

    const int nn = (n < KNB) ? n : KNB;
    const int nbrv = (lane < nn) ? ci[lane] : -1;
    s_valid[lane] = (lane < nn) ? 1 : 0;

    // ---- gather msg = [x_j | rel | 0-pad] as bf16
#pragma unroll 4
    for (int i = 0; i < 16; ++i) {
      const int k = wave * 16 + i;
      const int j = __shfl(nbrv, k, 64);
      float f = 0.f;
      if (j >= 0) f = x[(size_t)(base + j) * 64 + lane];
      s_msg[k][lane] = f2bf(f);
      if (lane < 40) {
        float rv = 0.f;
        if (lane < 3 && j >= 0) {
          float p = pos[(size_t)(base + j) * 3 + lane];
          float qq = (lane == 0) ? q0 : ((lane == 1) ? q1 : q2);
          rv = __fsub_rn(p, qq);
        }
        s_msg[k][64 + lane] = f2bf(rv);
      }
    }
    __syncthreads();

    const int row = wave * 16 + (lane & 15);
    const int kofs = (lane >> 4) * 8;

    // ---- GEMM1
    short8_t a1[3];
#pragma unroll
    for (int kt = 0; kt < 3; ++kt)
      a1[kt] = *(const short8_t*)&s_msg[row][kt * 32 + kofs];
    f32x4 acc1[8];
#pragma unroll
    for (int nt = 0; nt < 8; ++nt) acc1[nt] = (f32x4){0.f, 0.f, 0.f, 0.f};
#pragma unroll
    for (int kt = 0; kt < 3; ++kt) {
#pragma unroll
      for (int nt = 0; nt < 8; ++nt) {
        short8_t bf = *(const short8_t*)&w1f[((nt * 3 + kt) * 64 + lane) * 8];
        acc1[nt] = __builtin_amdgcn_mfma_f32_16x16x32_bf16(a1[kt], bf, acc1[nt], 0, 0, 0);
      }
    }
#pragma unroll
    for (int nt = 0; nt < 8; ++nt) {
      const int n2 = nt * 16 + (lane & 15);
      const float bias = b1[n2];
      f32x4 v = acc1[nt];
#pragma unroll
      for (int e = 0; e < 4; ++e) {
        const int mm2 = wave * 16 + (lane >> 4) * 4 + e;
        float h = v[e] + bias;
        h = (h > 0.f) ? h : 0.f;
        s_h1[mm2][n2] = f2bf(h);
      }
    }
    __syncthreads();

    // ---- GEMM2 + mask + max over k
    short8_t a2[4];
#pragma unroll
    for (int kt = 0; kt < 4; ++kt)
      a2[kt] = *(const short8_t*)&s_h1[row][kt * 32 + kofs];
    f32x4 acc2[16];
#pragma unroll
    for (int nt = 0; nt < 16; ++nt) acc2[nt] = (f32x4){0.f, 0.f, 0.f, 0.f};
#pragma unroll
    for (int kt = 0; kt < 4; ++kt) {
#pragma unroll
      for (int nt = 0; nt < 16; ++nt) {
        short8_t bf = *(const short8_t*)&w2f[((nt * 4 + kt) * 64 + lane) * 8];
        acc2[nt] = __builtin_amdgcn_mfma_f32_16x16x32_bf16(a2[kt], bf, acc2[nt], 0, 0, 0);
      }
    }
    const int m0i = wave * 16 + (lane >> 4) * 4;
    const int vld0 = s_valid[m0i + 0], vld1 = s_valid[m0i + 1];
    const int vld2 = s_valid[m0i + 2], vld3 = s_valid[m0i + 3];
#pragma unroll
    for (int nt = 0; nt < 16; ++nt) {
      const int n2 = nt * 16 + (lane & 15);
      const float bias = b2[n2];
      f32x4 d = acc2[nt];
      float best = -__builtin_inff();
      {
        float h;
        h = d[0] + bias; h = (h > 0.f) ? h : 0.f; if (vld0) best = fmaxf(best, h);
        h = d[1] + bias; h = (h > 0.f) ? h : 0.f; if (vld1) best = fmaxf(best, h);
        h = d[2] + bias; h = (h > 0.f) ? h : 0.f; if (vld2) best = fmaxf(best, h);
        h = d[3] + bias; h = (h > 0.f) ? h : 0.f; if (vld3) best = fmaxf(best, h);
      }
      best = fmaxf(best, __shfl_xor(best, 16, 64));
      best = fmaxf(best, __shfl_xor(best, 32, 64));
      if ((lane >> 4) == 0) s_red[wave][n2] = best;
    }
    __syncthreads();
    const float r = fmaxf(fmaxf(s_red[0][t], s_red[1][t]), fmaxf(s_red[2][t], s_red[3][t]));
    out[(size_t)c * 256 + t] = r;

    // ---- tail for this centroid
    if (t < 5) {
      const int g = base + qi;
      float* pos_out = out + 1048576;
      float* batch_out = out + 1048576 + 12288;
      float* w_out = out + 1048576 + 12288 + 4096;
      if (t < 3)      pos_out[c * 3 + t] = pos[(size_t)g * 3 + t];
      else if (t == 3) batch_out[c] = (float)cloud;
      else             w_out[c] = weight[g];
    }
    __syncthreads();   // all threads done with LDS before next item resets
  }
}

extern "C" void kernel_launch(void* const* d_in, const int* in_sizes, int n_in,
                              void* d_out, int out_size, void* d_ws, size_t ws_size,
                              hipStream_t stream) {
  const float* x      = (const float*)d_in[0];
  const float* pos    = (const float*)d_in[1];
  // d_in[2] = batch (unused: batch = global_index / NPER by construction)
  const float* weight = (const float*)d_in[3];
  const float* W1     = (const float*)d_in[4];
  const float* b1     = (const float*)d_in[5];
  const float* W2     = (const float*)d_in[6];
  const float* b2     = (const float*)d_in[7];
  float* out = (float*)d_out;

  char* ws = (char*)d_ws;
  int* idxg = (int*)ws;                                    // 4096 * 4B (sentinel -1)
  unsigned short* w1f = (unsigned short*)(ws + 16384);     // 12288 * 2B
  unsigned short* w2f = (unsigned short*)(ws + 40960);     // 32768 * 2B
  int* control = (int*)(ws + 106496);                      // ctr @0

  prep_kernel<<<193, 256, 0, stream>>>(W1, W2, w1f, w2f, idxg, control);
  fused_kernel<<<NWORK, 256, 0, stream>>>(x, pos, weight, w1f, w2f, b1, b2,
                                          idxg, control, out);
}